// Round 9
// baseline (262.198 us; speedup 1.0000x reference)
//
#include <hip/hip_runtime.h>
#include <hip/hip_bf16.h>
#include <stdint.h>

// Correlation (FlowNet), md=4: out[b, di*9+dj, h, w] = sum_c x[b,c,h,w]*yp[b,c,h+di-4,w+dj-4] / 256
// R8: di-SPLIT across blocks (dg=0..2, di=dg*3+dl). acc 72->24 regs, y-LDS 10 rows
// (40KB dbuf), ~3 independent blocks/CU breaking the barrier-convoy latency floor.
// dg-siblings + hq-neighbors dispatch-adjacent on the same XCD for L2 sharing.

using f32x4 = __attribute__((ext_vector_type(4))) float;
using s16x4 = __attribute__((ext_vector_type(4))) short;
using u16x4 = __attribute__((ext_vector_type(4))) unsigned short;

#define C_DIM 256
#define H_DIM 96
#define W_DIM 192
#define HWSZ  (H_DIM * W_DIM)
#define MD 4
#define KD 9
#define NDG 3                    // di groups per pixel-tile
#define CHUNK 32
#define NCHUNK 8
#define NTHR 512
#define WTILES 12                // 192/16
#define HQ 12                    // 96/8
#define SUB_B 128                // [4c][16s] bf16 subtile, 128B-aligned (tr native)
#define YROW_B (16 * SUB_B)      // 2048 B per y row: 2 s-tiles x 8 cg x 128B
#define NROWS 10                 // y rows h0-4+dg*3 .. h0+5+dg*3
#define BUFSZ (NROWS * YROW_B)   // 20480
#define LDS_BYTES (2 * BUFSZ)    // 40960
#define NYQ (NROWS * CHUNK * 6)  // 1920 staged 16B-quads per chunk

static __device__ __forceinline__ unsigned short bf16b(float f) {
  __bf16 h = (__bf16)f;                   // RNE
  unsigned short s; __builtin_memcpy(&s, &h, 2); return s;
}

static __device__ __forceinline__ s16x4 tr16(uint32_t addr) {
  s16x4 d;
  asm volatile("ds_read_b64_tr_b16 %0, %1" : "=v"(d) : "v"(addr));
  return d;
}

#define WAITLG(n) asm volatile("s_waitcnt lgkmcnt(" #n ")" ::: "memory")

__global__ __launch_bounds__(NTHR, 5)
void corr_mfma(const float* __restrict__ xg, const float* __restrict__ yg,
               float* __restrict__ outg) {
  __shared__ __align__(16) char smem[LDS_BYTES];

  const int bid = blockIdx.x;             // 3456 = 12*12*3*8
  const int b   = bid & 7;                // XCD round-robin
  const int r2  = bid >> 3;
  const int dg  = r2 % NDG;               // di group (siblings 8 bids apart: same XCD)
  const int r3  = r2 / NDG;
  const int hq  = r3 % HQ;                // hq next: halo neighbors 24 apart, same XCD
  const int wt  = r3 / HQ;
  const int w0  = wt * 16;
  const int h0  = hq * 8;
  const int yr0 = h0 - MD + dg * NDG;     // global y row of LDS row 0

  const int tid  = threadIdx.x;
  const int lane = tid & 63;
  const int wv   = tid >> 6;              // 0..7 -> output row h0+wv
  const int hi   = lane >> 4;
  const int lm   = lane & 15;

  const uint32_t sbase = (uint32_t)(uintptr_t)&smem[0];

  // ---- y staging decode, hoisted: 1920 quads; slots 0..2 full, slot 3 tid<384
  uint32_t goffY[4], loffY[4];
  uint32_t vmY = 0, exY = 0;
#pragma unroll
  for (int i = 0; i < 4; ++i) {
    const int qid = i * NTHR + tid;
    goffY[i] = 0u; loffY[i] = 0u;
    if (qid < NYQ) {
      exY |= (1u << i);
      const int q = qid % 6;
      const int c = (qid / 6) & 31;
      const int r = qid / 192;            // 0..9 -> y row yr0+r
      const int hg = yr0 + r;
      const int sg = w0 - MD + 4 * q;     // 4-aligned: OOB is whole-quad
      const bool ok = (hg >= 0) && (hg < H_DIM) && (sg >= 0) && (sg < W_DIM);
      if (ok) vmY |= (1u << i);
      goffY[i] = ok ? (uint32_t)(((b * C_DIM + c) * H_DIM + hg) * W_DIM + sg) : 0u;
      const int s = 4 * q;
      loffY[i] = r * YROW_B + (s >> 4) * 1024 + (c >> 2) * SUB_B + (c & 3) * 32 + (s & 15) * 2;
    }
  }

  // ---- x global-direct A-frags: lane (hi,lm) reads c = c0 + kh*16 + hi*4 + e at (h, w0+lm)
  const int h = h0 + wv;
  uint32_t xoff[8];
#pragma unroll
  for (int e = 0; e < 8; ++e) {
    const int ce = (e < 4) ? (hi * 4 + e) : (16 + hi * 4 + (e - 4));
    xoff[e] = (uint32_t)(((b * C_DIM + ce) * H_DIM + h) * W_DIM + w0 + lm);
  }

  f32x4 acc[NDG][2];
#pragma unroll
  for (int dl = 0; dl < NDG; ++dl) {
    acc[dl][0] = f32x4{0.f, 0.f, 0.f, 0.f};
    acc[dl][1] = f32x4{0.f, 0.f, 0.f, 0.f};
  }

  // B tr base: y LDS row for (wv, dl) is wv + dl (global yr0+wv+dl = h+dg*3+dl-4)
  const uint32_t bbase = sbase + (uint32_t)wv * YROW_B + hi * SUB_B + lm * 8;

  float4 yv[4];
  float  xv[8];
  s16x4  afr0, afr1;

  // ---- prologue: chunk 0 load + cvt + write + afr(0)
  {
#pragma unroll
    for (int i = 0; i < 4; ++i) {
      float4 t4 = make_float4(0.f, 0.f, 0.f, 0.f);
      if (vmY & (1u << i)) t4 = *(const float4*)(yg + goffY[i]);
      yv[i] = t4;
    }
#pragma unroll
    for (int e = 0; e < 8; ++e) xv[e] = xg[xoff[e]];
#pragma unroll
    for (int i = 0; i < 4; ++i)
      if (exY & (1u << i))
        *(u16x4*)(smem + loffY[i]) =
            u16x4{bf16b(yv[i].x), bf16b(yv[i].y), bf16b(yv[i].z), bf16b(yv[i].w)};
    afr0[0] = (short)bf16b(xv[0]); afr0[1] = (short)bf16b(xv[1]);
    afr0[2] = (short)bf16b(xv[2]); afr0[3] = (short)bf16b(xv[3]);
    afr1[0] = (short)bf16b(xv[4]); afr1[1] = (short)bf16b(xv[5]);
    afr1[2] = (short)bf16b(xv[6]); afr1[3] = (short)bf16b(xv[7]);
  }
  __syncthreads();

  for (int t = 0; t < NCHUNK; ++t) {
    // ---- 1. issue chunk t+1 loads (compute phase + sibling blocks cover latency)
    if (t + 1 < NCHUNK) {
      const uint32_t co = (uint32_t)(t + 1) * CHUNK * HWSZ;
#pragma unroll
      for (int i = 0; i < 4; ++i) {
        float4 t4 = make_float4(0.f, 0.f, 0.f, 0.f);
        if (vmY & (1u << i)) t4 = *(const float4*)(yg + goffY[i] + co);
        yv[i] = t4;
      }
#pragma unroll
      for (int e = 0; e < 8; ++e) xv[e] = xg[xoff[e] + co];
    }

    // ---- 2. compute chunk t from buf[t&1]
    const uint32_t bo = (uint32_t)(t & 1) * BUFSZ;
    s16x4 bsl[2][4];

#define ISSUE_DL(dl) { \
    const uint32_t ba = bbase + bo + (uint32_t)(dl) * YROW_B; \
    bsl[(dl) & 1][0] = tr16(ba);          /* t0 kh0 */ \
    bsl[(dl) & 1][1] = tr16(ba + 512);    /* t0 kh1 */ \
    bsl[(dl) & 1][2] = tr16(ba + 1024);   /* t1 kh0 */ \
    bsl[(dl) & 1][3] = tr16(ba + 1536); } /* t1 kh1 */

#define DO_DL(dl, lg) \
    WAITLG(lg); __builtin_amdgcn_sched_barrier(0); \
    acc[dl][0] = __builtin_amdgcn_mfma_f32_16x16x16bf16_1k(afr0, bsl[(dl) & 1][0], acc[dl][0], 0, 0, 0); \
    acc[dl][0] = __builtin_amdgcn_mfma_f32_16x16x16bf16_1k(afr1, bsl[(dl) & 1][1], acc[dl][0], 0, 0, 0); \
    acc[dl][1] = __builtin_amdgcn_mfma_f32_16x16x16bf16_1k(afr0, bsl[(dl) & 1][2], acc[dl][1], 0, 0, 0); \
    acc[dl][1] = __builtin_amdgcn_mfma_f32_16x16x16bf16_1k(afr1, bsl[(dl) & 1][3], acc[dl][1], 0, 0, 0);

    __builtin_amdgcn_s_setprio(1);
    ISSUE_DL(0)
    ISSUE_DL(1)
    DO_DL(0, 4)
    ISSUE_DL(2)
    DO_DL(1, 4)
    DO_DL(2, 0)
    __builtin_amdgcn_s_setprio(0);
#undef ISSUE_DL
#undef DO_DL

    // ---- 3. cvt (vmcnt wait lands here) + write buf[(t+1)&1] + next afr
    if (t + 1 < NCHUNK) {
      const uint32_t wo = (uint32_t)((t + 1) & 1) * BUFSZ;
#pragma unroll
      for (int i = 0; i < 4; ++i)
        if (exY & (1u << i))
          *(u16x4*)(smem + wo + loffY[i]) =
              u16x4{bf16b(yv[i].x), bf16b(yv[i].y), bf16b(yv[i].z), bf16b(yv[i].w)};
      afr0[0] = (short)bf16b(xv[0]); afr0[1] = (short)bf16b(xv[1]);
      afr0[2] = (short)bf16b(xv[2]); afr0[3] = (short)bf16b(xv[3]);
      afr1[0] = (short)bf16b(xv[4]); afr1[1] = (short)bf16b(xv[5]);
      afr1[2] = (short)bf16b(xv[6]); afr1[3] = (short)bf16b(xv[7]);
    }
    // ---- 4. barrier (vmcnt drained at cvt; lgkm writes drain in barrier)
    __syncthreads();
  }

  // ---- epilogue: D[m][n]: n=lm, m=hi*4+rg (verified). dj = tt*16 + lm - m.
  const float scale = 1.f / 256.f;
#pragma unroll
  for (int dl = 0; dl < NDG; ++dl) {
    const int di = dg * NDG + dl;
#pragma unroll
    for (int tt = 0; tt < 2; ++tt) {
#pragma unroll
      for (int rg = 0; rg < 4; ++rg) {
        const int m = hi * 4 + rg;
        const int dj = tt * 16 + lm - m;
        if (0 <= dj && dj <= 8) {
          outg[((b * (KD * KD) + di * KD + dj) * H_DIM + h) * W_DIM + w0 + m] =
              acc[dl][tt][rg] * scale;
        }
      }
    }
  }
}

extern "C" void kernel_launch(void* const* d_in, const int* in_sizes, int n_in,
                              void* d_out, int out_size, void* d_ws, size_t ws_size,
                              hipStream_t stream) {
  const float* x = (const float*)d_in[0];
  const float* y = (const float*)d_in[1];
  float* out = (float*)d_out;
  (void)in_sizes; (void)n_in; (void)d_ws; (void)ws_size; (void)out_size;

  const int grid = WTILES * HQ * NDG * 8; // 3456 blocks, 512 threads
  corr_mfma<<<dim3(grid), dim3(NTHR), 0, stream>>>(x, y, out);
}

// Round 10
// 139.435 us; speedup vs baseline: 1.8804x; 1.8804x over previous
//
#include <hip/hip_runtime.h>
#include <hip/hip_bf16.h>
#include <stdint.h>

// Correlation (FlowNet), md=4: out[b, di*9+dj, h, w] = sum_c x[b,c,h,w]*yp[b,c,h+di-4,w+dj-4] / 256
// R9 = R1 (the 140us champion) with exactly ONE change: SUB_B 160 -> 128, making
// every [4c][16s] bf16 tr-subtile 128B-aligned/contiguous (R2 measured 4x fewer
// bank conflicts). Everything else byte-identical to R1: HR=8, CHUNK=32,
// x staged in LDS, single-buffered, loads->cvt->sync->write->sync->compute.

using f32x4 = __attribute__((ext_vector_type(4))) float;
using s16x4 = __attribute__((ext_vector_type(4))) short;
using u16x4 = __attribute__((ext_vector_type(4))) unsigned short;

#define C_DIM 256
#define H_DIM 96
#define W_DIM 192
#define HWSZ  (H_DIM * W_DIM)
#define MD 4
#define KD 9
#define CHUNK 32
#define HR 8
#define NTHR 512
#define WTILES 12          // 192/16
#define HQ 12              // 96/8
#define SUB_B 128          // [4c][16s] bf16 subtile = 128B, aligned (tr native)
#define YROW_B (16 * SUB_B)   // 2 t * 8 cg subtiles = 2048B per y row
#define XROW_B (8 * SUB_B)    // t=0 only = 1024B per x row
#define XBASE  (16 * YROW_B)  // 32768
#define LDS_BYTES (XBASE + 8 * XROW_B)   // 40960

static __device__ __forceinline__ unsigned short bf16b(float f) {
  __bf16 h = (__bf16)f;                   // RNE
  unsigned short s; __builtin_memcpy(&s, &h, 2); return s;
}

// per-lane: reads column (l&15) of the [4c][16s] bf16 subtile at its address
static __device__ __forceinline__ s16x4 tr16(uint32_t addr) {
  s16x4 d;
  asm volatile("ds_read_b64_tr_b16 %0, %1" : "=v"(d) : "v"(addr));
  return d;
}

__global__ __launch_bounds__(NTHR, 4)
void corr_mfma(const float* __restrict__ xg, const float* __restrict__ yg,
               float* __restrict__ outg) {
  __shared__ __align__(16) char smem[LDS_BYTES];

  const int bid = blockIdx.x;             // 1152 = 8 * 144
  const int b   = bid & 7;                // batch == XCD (round-robin dispatch)
  const int rem = bid >> 3;               // 0..143, hq fastest -> h-halo L2 reuse
  const int wt  = rem / HQ;
  const int hq  = rem - wt * HQ;
  const int w0  = wt * 16;
  const int h0  = hq * HR;

  const int tid  = threadIdx.x;
  const int lane = tid & 63;
  const int wv   = tid >> 6;              // wave id 0..7 -> output row h0+wv
  const int hi   = lane >> 4;
  const int lm   = lane & 15;

  const uint32_t sbase = (uint32_t)(uintptr_t)&smem[0];  // LDS aperture 4GB-aligned

  // ---- staging decode, hoisted. i<6: y quads (16 rows x 32c x 6q); i 6,7: x (8 x 32c x 4q)
  uint32_t goffY[6], loffY[6], goffX[2], loffX[2];
  uint32_t vmaskY = 0;
#pragma unroll
  for (int i = 0; i < 6; ++i) {
    const int qid = i * NTHR + tid;
    const int q = qid % 6;
    const int c = (qid / 6) % CHUNK;
    const int r = qid / 192;              // y row 0..15 -> h0+r-4
    const int hg = h0 + r - MD;
    const int sg = w0 - MD + 4 * q;       // 4-aligned -> OOB is whole-quad only
    const bool ok = (hg >= 0) && (hg < H_DIM) && (sg >= 0) && (sg < W_DIM);
    if (ok) vmaskY |= (1u << i);
    goffY[i] = ok ? (uint32_t)(((b * C_DIM + c) * H_DIM + hg) * W_DIM + sg) : 0u;
    const int s = 4 * q;                  // local s 0..20
    loffY[i] = r * YROW_B + (s >> 4) * (8 * SUB_B) + (c >> 2) * SUB_B
             + (c & 3) * 32 + (s & 15) * 2;
  }
#pragma unroll
  for (int i = 0; i < 2; ++i) {
    const int qid = i * NTHR + tid;
    const int q = qid & 3;                // x staged without w-halo: s = w-w0
    const int c = (qid >> 2) & 31;
    const int r = qid >> 7;               // 0..7 -> h0+r
    goffX[i] = (uint32_t)(((b * C_DIM + c) * H_DIM + (h0 + r)) * W_DIM + (w0 + 4 * q));
    loffX[i] = XBASE + r * XROW_B + (c >> 2) * SUB_B + (c & 3) * 32 + 8 * q;
  }

  f32x4 acc[KD][2];
#pragma unroll
  for (int di = 0; di < KD; ++di) {
    acc[di][0] = f32x4{0.f, 0.f, 0.f, 0.f};
    acc[di][1] = f32x4{0.f, 0.f, 0.f, 0.f};
  }

  // fragment base addresses: subtile cg = kh*4+hi holds channels kh*16+hi*4..+3
  const uint32_t abase = sbase + XBASE + wv * XROW_B + hi * SUB_B + lm * 8;
  const uint32_t bbase = sbase + wv * YROW_B + hi * SUB_B + lm * 8;

  for (int c0 = 0; c0 < C_DIM; c0 += CHUNK) {
    // ---- global loads + convert (before barrier: overlaps other waves' compute)
    u16x4 wbuf[8];
#pragma unroll
    for (int i = 0; i < 6; ++i) {
      float4 v = make_float4(0.f, 0.f, 0.f, 0.f);
      if (vmaskY & (1u << i)) v = *(const float4*)(yg + goffY[i] + (uint32_t)c0 * HWSZ);
      wbuf[i] = u16x4{bf16b(v.x), bf16b(v.y), bf16b(v.z), bf16b(v.w)};
    }
#pragma unroll
    for (int i = 0; i < 2; ++i) {
      float4 v = *(const float4*)(xg + goffX[i] + (uint32_t)c0 * HWSZ);
      wbuf[6 + i] = u16x4{bf16b(v.x), bf16b(v.y), bf16b(v.z), bf16b(v.w)};
    }

    __syncthreads();                      // previous chunk's LDS reads done
#pragma unroll
    for (int i = 0; i < 6; ++i) *(u16x4*)(smem + loffY[i]) = wbuf[i];
#pragma unroll
    for (int i = 0; i < 2; ++i) *(u16x4*)(smem + loffX[i]) = wbuf[6 + i];
    __syncthreads();

    // ---- A fragments: x row (LDS row wv), col w0+lm
    s16x4 afr0 = tr16(abase);
    s16x4 afr1 = tr16(abase + 4 * SUB_B);
    s16x4 bc0 = tr16(bbase);
    s16x4 bc1 = tr16(bbase + 4 * SUB_B);
    s16x4 bc2 = tr16(bbase + 8 * SUB_B);
    s16x4 bc3 = tr16(bbase + 12 * SUB_B);
#pragma unroll
    for (int di = 0; di < KD; ++di) {
      s16x4 bn0, bn1, bn2, bn3;
      if (di < 8) {
        const uint32_t bb = bbase + (uint32_t)(di + 1) * YROW_B;  // y row wv+di+1
        bn0 = tr16(bb);
        bn1 = tr16(bb + 4 * SUB_B);
        bn2 = tr16(bb + 8 * SUB_B);
        bn3 = tr16(bb + 12 * SUB_B);
        asm volatile("s_waitcnt lgkmcnt(4)" ::: "memory");  // cur frags (+A) done
      } else {
        asm volatile("s_waitcnt lgkmcnt(0)" ::: "memory");
      }
      __builtin_amdgcn_sched_barrier(0);  // rule #18: don't hoist MFMA past waitcnt
      acc[di][0] = __builtin_amdgcn_mfma_f32_16x16x16bf16_1k(afr0, bc0, acc[di][0], 0, 0, 0);
      acc[di][0] = __builtin_amdgcn_mfma_f32_16x16x16bf16_1k(afr1, bc1, acc[di][0], 0, 0, 0);
      acc[di][1] = __builtin_amdgcn_mfma_f32_16x16x16bf16_1k(afr0, bc2, acc[di][1], 0, 0, 0);
      acc[di][1] = __builtin_amdgcn_mfma_f32_16x16x16bf16_1k(afr1, bc3, acc[di][1], 0, 0, 0);
      if (di < 8) { bc0 = bn0; bc1 = bn1; bc2 = bn2; bc3 = bn3; }
    }
  }

  // ---- epilogue: D[m][n]: n=lm, m=hi*4+rg (verified). dj = t*16 + lm - m.
  const int h = h0 + wv;
  const float scale = 1.f / 256.f;
#pragma unroll
  for (int di = 0; di < KD; ++di) {
#pragma unroll
    for (int t = 0; t < 2; ++t) {
#pragma unroll
      for (int rg = 0; rg < 4; ++rg) {
        const int m = hi * 4 + rg;
        const int dj = t * 16 + lm - m;
        if (0 <= dj && dj <= 8) {
          outg[((b * (KD * KD) + di * KD + dj) * H_DIM + h) * W_DIM + w0 + m] =
              acc[di][t][rg] * scale;
        }
      }
    }
  }
}

extern "C" void kernel_launch(void* const* d_in, const int* in_sizes, int n_in,
                              void* d_out, int out_size, void* d_ws, size_t ws_size,
                              hipStream_t stream) {
  const float* x = (const float*)d_in[0];
  const float* y = (const float*)d_in[1];
  float* out = (float*)d_out;
  (void)in_sizes; (void)n_in; (void)d_ws; (void)ws_size; (void)out_size;

  const int grid = 8 * HQ * WTILES;       // 1152 blocks, 512 threads
  corr_mfma<<<dim3(grid), dim3(NTHR), 0, stream>>>(x, y, out);
}